// Round 19
// baseline (2823.960 us; speedup 1.0000x reference)
//
#include <hip/hip_runtime.h>
#include <stdint.h>

#define NE    8
#define HID   2048
#define INTER 7168
#define TTOK  8192
#define NT1   (HID / 64)    // 32 K-tiles for pass1
#define NT2   (INTER / 64)  // 112 K-tiles for pass2

typedef __bf16 bf16;
typedef bf16 bf16x4 __attribute__((ext_vector_type(4)));
typedef bf16 bf16x8 __attribute__((ext_vector_type(8)));
typedef float f32x16 __attribute__((ext_vector_type(16)));

__device__ __forceinline__ void glds16(const void* g, void* l) {
  __builtin_amdgcn_global_load_lds((__attribute__((address_space(1))) void*)g,
                                   (__attribute__((address_space(3))) void*)l, 16, 0, 0);
}

// ---------------- fused: w1/w3 fp32->bf16 cvt + router (+ bf16 x) ----------------
__global__ void cvtrt_kernel(const float* __restrict__ w1, const float* __restrict__ w3,
                             bf16* __restrict__ wdst,
                             const float* __restrict__ x, const float* __restrict__ gw,
                             bf16* __restrict__ xb,
                             int* __restrict__ topk_e, float* __restrict__ topk_w) {
  const long SEG = (long)NE * INTER * HID;
  if (blockIdx.x < 8192) {
    const int seg = blockIdx.x >> 12;
    const int bid = blockIdx.x & 4095;
    const float* src = seg ? w3 : w1;
    bf16* d = wdst + (size_t)seg * SEG;
    long i = (long)bid * blockDim.x + threadIdx.x;
    const long stride = (long)4096 * blockDim.x;
    for (long j = i * 4; j < SEG; j += stride * 4) {
      float4 v = *(const float4*)(src + j);
      bf16x4 o = {(bf16)v.x, (bf16)v.y, (bf16)v.z, (bf16)v.w};
      *(bf16x4*)(d + j) = o;
    }
    return;
  }
  const int rb = blockIdx.x - 8192;
  const int wid = threadIdx.x >> 6, lane = threadIdx.x & 63;
  const int t = rb * 4 + wid;
  if (t >= TTOK) return;
  const float* xr = x + (size_t)t * HID;
  bf16* xw = xb + (size_t)t * HID;
  float xv[32];
#pragma unroll
  for (int i = 0; i < 32; ++i) xv[i] = xr[lane + 64 * i];
#pragma unroll
  for (int i = 0; i < 32; ++i) xw[lane + 64 * i] = (bf16)xv[i];
  float lg[NE];
#pragma unroll
  for (int e = 0; e < NE; ++e) {
    const float* g = gw + e * HID;
    float s = 0.f;
#pragma unroll
    for (int i = 0; i < 32; ++i) s += xv[i] * g[lane + 64 * i];
#pragma unroll
    for (int off = 32; off; off >>= 1) s += __shfl_down(s, off);
    lg[e] = s;
  }
  if (lane == 0) {
    int i1 = 0;
#pragma unroll
    for (int e = 1; e < NE; ++e) if (lg[e] > lg[i1]) i1 = e;
    int i2 = (i1 == 0) ? 1 : 0;
#pragma unroll
    for (int e = 0; e < NE; ++e) if (e != i2 && e != i1 && lg[e] > lg[i2]) i2 = e;
    float r = __expf(lg[i2] - lg[i1]);
    float wa = 1.f / (1.f + r);
    topk_e[2 * t] = i1; topk_e[2 * t + 1] = i2;
    topk_w[2 * t] = wa; topk_w[2 * t + 1] = 1.f - wa;
  }
}

// ---------------- stable sorted gather (wave-scan) + inverse map ----------------
__global__ void gather_sorted(const int* __restrict__ topk_e, const float* __restrict__ topk_w,
                              int* __restrict__ cnt, int* __restrict__ ltok,
                              float* __restrict__ lw, int* __restrict__ ppos) {
  const int e = blockIdx.x;
  const int tid = threadIdx.x;
  const int lane = tid & 63, wv = tid >> 6;
  __shared__ int wtot[4];
  __shared__ int basesh;
  if (tid == 0) basesh = 0;
  __syncthreads();
  for (int c0 = 0; c0 < TTOK; c0 += 256) {
    const int t = c0 + tid;
    const int e0 = topk_e[2 * t], e1 = topk_e[2 * t + 1];
    const int j = (e0 == e) ? 0 : 1;
    const int flag = (e0 == e) || (e1 == e);
    unsigned long long b = __ballot(flag);
    int wrank = __popcll(b & ((1ULL << lane) - 1ULL));
    if (lane == 63) wtot[wv] = __popcll(b);
    __syncthreads();
    int wbase = 0;
#pragma unroll
    for (int k = 0; k < 4; ++k) if (k < wv) wbase += wtot[k];
    const int total = wtot[0] + wtot[1] + wtot[2] + wtot[3];
    const int pos = basesh + wbase + wrank;
    if (flag) {
      ltok[e * TTOK + pos] = t;
      lw[e * TTOK + pos] = (j == 0) ? topk_w[2 * t] : topk_w[2 * t + 1];
      ppos[2 * t + j] = pos;
    }
    __syncthreads();
    if (tid == 0) basesh += total;
    __syncthreads();
  }
  if (tid == 0) cnt[e] = basesh;
}

// ---------------- combine: out[t] = y[pair0(t)] + y[pair1(t)]  (bf16 ybuf) ----------------
__global__ void combine_kernel(const bf16* __restrict__ ybuf, const int* __restrict__ topk_e,
                               const int* __restrict__ ppos, const int* __restrict__ cnt,
                               float* __restrict__ out) {
  __shared__ int pref[NE];
  if (threadIdx.x < NE) {
    int b = 0;
    for (int k = 0; k < (int)threadIdx.x; ++k) b += cnt[k];
    pref[threadIdx.x] = b;
  }
  __syncthreads();
  const int t = blockIdx.x;
  const int col = threadIdx.x * 8;
  const int g0 = pref[topk_e[2 * t]] + ppos[2 * t];
  const int g1 = pref[topk_e[2 * t + 1]] + ppos[2 * t + 1];
  bf16x8 y0 = *(const bf16x8*)(ybuf + (size_t)g0 * HID + col);
  bf16x8 y1 = *(const bf16x8*)(ybuf + (size_t)g1 * HID + col);
  float4 o0, o1;
  o0.x = (float)y0[0] + (float)y1[0]; o0.y = (float)y0[1] + (float)y1[1];
  o0.z = (float)y0[2] + (float)y1[2]; o0.w = (float)y0[3] + (float)y1[3];
  o1.x = (float)y0[4] + (float)y1[4]; o1.y = (float)y0[5] + (float)y1[5];
  o1.z = (float)y0[6] + (float)y1[6]; o1.w = (float)y0[7] + (float)y1[7];
  float4* o = (float4*)(out + (size_t)t * HID + col);
  o[0] = o0; o[1] = o1;
}

// ============ 256x256 GEMM, 32x32x16 MFMA, 2-phase, FRAGMENT-LINEAR LDS ============
// LDS per half (128 rows x 64 cols): chunk c = g*256 + q*32 + r (g: 32-row group,
// q: k-octet, r: row-in-group), chunk addr = c*16. glds16 dest stays linear
// (tid*16 / (tid+512)*16); the GLOBAL source is permuted per-thread to realize the
// layout (both-sides rule). Read by lane l at (frag, ks): frag*4096 +
// (ks*2 + l>>5)*512 + (l&31)*16 -> 64 lanes read 1KB CONTIGUOUS = 0 bank conflicts
// (fixes r5's 9.2e7). Schedule = r5's audited race-free 2-phase (4 barriers/K-tile):
//  ph1: reads aLo+b; LGKM0; BAR; stage B1(t+1)[other buf]; 16 MFMA; BAR
//  ph2: reads aHi;   LGKM0; BAR; stage A0,A1,B0(t+2); 16 MFMA; vmcnt(6|0); BAR
// vmcnt(6) at ph2 keeps [A(t+2):4, B0(t+2):2], drains B1(t+1) and older.

#define MFMA32(a, b, c) __builtin_amdgcn_mfma_f32_32x32x16_bf16((a), (b), (c), 0, 0, 0)

#define STAGE_A(h, kt) do { int _b = ((kt) & 1) * 32768; size_t _k = (size_t)(kt) * 128; \
    glds16(bA + oA[(h)*2 + 0] + _k, ldsA + _b + (h) * 16384 + d0); \
    glds16(bA + oA[(h)*2 + 1] + _k, ldsA + _b + (h) * 16384 + d1); } while (0)
#define STAGE_B(h, kt) do { int _b = ((kt) & 1) * 32768; size_t _k = (size_t)(kt) * 128; \
    glds16(bB + oB[(h)*2 + 0] + _k, ldsB + _b + (h) * 16384 + d0); \
    glds16(bB + oB[(h)*2 + 1] + _k, ldsB + _b + (h) * 16384 + d1); } while (0)

#define RD_A(mf, ks) (*(const bf16x8*)(ldsA + curb + aOff + (mf) * 4096 + kcq[ks]))
#define RD_B(nf, ks) (*(const bf16x8*)(ldsB + curb + bOff + (nf) * 4096 + kcq[ks]))

#define BAR()    __builtin_amdgcn_s_barrier()
#define LGKM0()  do { asm volatile("s_waitcnt lgkmcnt(0)" ::: "memory"); \
                      __builtin_amdgcn_sched_barrier(0); } while (0)
#define SCHED0() __builtin_amdgcn_sched_barrier(0)

#define Q_MFMA32(AM, ACCM) do { \
  __builtin_amdgcn_s_setprio(1); \
  _Pragma("unroll") \
  for (int ks = 0; ks < 4; ++ks) \
    _Pragma("unroll") \
    for (int m = 0; m < 2; ++m) \
      _Pragma("unroll") \
      for (int n = 0; n < 2; ++n) \
        acc[ACCM + m][n] = MFMA32(AM[m][ks], bF[n][ks], acc[ACCM + m][n]); \
  __builtin_amdgcn_s_setprio(0); \
} while (0)

// ---------------- pass1: h = silu(x w1^T) * (x w3^T)  (+ z==NE w2-cvt tail) ----------------
// B-tile 256 rows = 4 groups of 64: group i rows 0-31 = w1 (h-cols tn*128+i*32..+31),
// rows 32-63 = w3 same cols. Wave (wm=wid>>2, wn=wid&3): A rows wm*128+mf*32+ln31,
// B rows wn*64+nf*32+ln31 (nf: 0=g, 1=u) -> thread-local silu.
__launch_bounds__(512, 2)
__global__ void pass1_kernel(const bf16* __restrict__ xb, const bf16* __restrict__ w1b,
                             const float* __restrict__ w2f, bf16* __restrict__ w2b,
                             bf16* __restrict__ hbuf, const int* __restrict__ cnt,
                             const int* __restrict__ ltok) {
  if (blockIdx.z == NE) {
    const long n4 = (long)NE * HID * INTER / 4;
    long i = (long)(blockIdx.y * gridDim.x + blockIdx.x) * blockDim.x + threadIdx.x;
    const long stride = (long)gridDim.x * gridDim.y * blockDim.x;
    const float4* src = (const float4*)w2f;
    bf16x4* dst = (bf16x4*)w2b;
    for (long j = i; j < n4; j += stride) {
      float4 v = src[j];
      bf16x4 o = {(bf16)v.x, (bf16)v.y, (bf16)v.z, (bf16)v.w};
      dst[j] = o;
    }
    return;
  }
  const int e = blockIdx.z;
  const int c = cnt[e];
  const int tm = blockIdx.y;
  if (tm * 256 >= c) return;
  const int tn = blockIdx.x;
  int be = 0;
#pragma unroll
  for (int k = 0; k < NE; ++k) if (k < e) be += cnt[k];

  __shared__ __align__(16) bf16 sA[2][256 * 64];
  __shared__ __align__(16) bf16 sB[2][256 * 64];
  char* const ldsA = (char*)&sA[0][0];
  char* const ldsB = (char*)&sB[0][0];

  const int tid = threadIdx.x;
  const int d0 = tid * 16, d1 = (tid + 512) * 16;
  const char* const bA = (const char*)xb;
  const char* const bB = (const char*)w1b;  // w3b contiguous after w1b

  // staging source permutation: chunk c -> (g=c>>8, q=(c>>5)&7, r=c&31)
  uint32_t oA[4], oB[4];
#pragma unroll
  for (int j = 0; j < 2; ++j) {
    const int ch = j ? (tid + 512) : tid;
    const int g = ch >> 8, q = (ch >> 5) & 7, r = ch & 31;
#pragma unroll
    for (int h = 0; h < 2; ++h) {
      const int rowt = h * 128 + g * 32 + r;          // tile row 0..255
      int slot = tm * 256 + rowt; if (slot >= c) slot = c - 1;
      oA[h * 2 + j] = (uint32_t)((size_t)ltok[e * TTOK + slot] * (HID * 2) + q * 16);
      const int br = rowt;                             // B tile row
      const int w = (br >> 5) & 1;                     // 0: w1, 1: w3
      const int wr = tn * 128 + (br >> 6) * 32 + (br & 31);
      size_t off = ((size_t)e * INTER + wr) * (HID * 2) + (size_t)q * 16;
      if (w) off += (size_t)NE * INTER * HID * 2;
      oB[h * 2 + j] = (uint32_t)off;
    }
  }

  const int lane = tid & 63, wid = tid >> 6;
  const int wm = wid >> 2, wn = wid & 3;
  const int ln31 = lane & 31, kq2 = lane >> 5;
  int kcq[4];
#pragma unroll
  for (int ks = 0; ks < 4; ++ks) kcq[ks] = (ks * 2 + kq2) * 512;
  const int aOff = wm * 16384 + ln31 * 16;
  const int bOff = (wn >> 1) * 16384 + (wn & 1) * 8192 + ln31 * 16;

  f32x16 acc[4][2];
#pragma unroll
  for (int m = 0; m < 4; ++m)
#pragma unroll
    for (int n = 0; n < 2; ++n) acc[m][n] = (f32x16)(0.f);

  STAGE_A(0, 0); STAGE_A(1, 0); STAGE_B(0, 0); STAGE_B(1, 0);
  STAGE_A(0, 1); STAGE_A(1, 1); STAGE_B(0, 1);
  asm volatile("s_waitcnt vmcnt(6)" ::: "memory");
  BAR();

  bf16x8 aF[2][4], bF[2][4];
  int cur = 0;
  for (int t = 0; t < NT1; ++t, cur ^= 1) {
    const int curb = cur * 32768;
    // ---- ph1: read aLo(8)+b(8); stage B1(t+1); MFMA (m0,m1)x(g,u) ----
#pragma unroll
    for (int m = 0; m < 2; ++m)
#pragma unroll
      for (int ks = 0; ks < 4; ++ks) aF[m][ks] = RD_A(m, ks);
#pragma unroll
    for (int n = 0; n < 2; ++n)
#pragma unroll
      for (int ks = 0; ks < 4; ++ks) bF[n][ks] = RD_B(n, ks);
    LGKM0();
    BAR();
    if (t + 1 < NT1) { STAGE_B(1, t + 1); SCHED0(); }
    Q_MFMA32(aF, 0);
    BAR();
    // ---- ph2: read aHi(8); stage A0,A1,B0(t+2); MFMA (m2,m3)x(g,u) ----
#pragma unroll
    for (int m = 0; m < 2; ++m)
#pragma unroll
      for (int ks = 0; ks < 4; ++ks) aF[m][ks] = RD_A(2 + m, ks);
    LGKM0();
    BAR();
    if (t + 2 < NT1) { STAGE_A(0, t + 2); STAGE_A(1, t + 2); STAGE_B(0, t + 2); SCHED0(); }
    Q_MFMA32(aF, 2);
    if (t + 2 < NT1) asm volatile("s_waitcnt vmcnt(6)" ::: "memory");
    else             asm volatile("s_waitcnt vmcnt(0)" ::: "memory");
    BAR();
  }

  // epilogue: silu(g)*u; C/D: col=lane&31, row=(reg&3)+8*(reg>>2)+4*(lane>>5)
  const int hcol = tn * 128 + wn * 32 + ln31;
#pragma unroll
  for (int mf = 0; mf < 4; ++mf)
#pragma unroll
    for (int reg = 0; reg < 16; ++reg) {
      const int row = mf * 32 + (reg & 3) + 8 * (reg >> 2) + 4 * kq2;
      const int slot = tm * 256 + wm * 128 + row;
      if (slot < c) {
        const float g = acc[mf][0][reg];
        const float u = acc[mf][1][reg];
        const float hv = g / (1.f + __expf(-g)) * u;
        hbuf[(size_t)(be + slot) * INTER + hcol] = (bf16)hv;
      }
    }
}

// ---------------- pass2: ybuf[pair,:] = w * (h w2^T), bf16 out ----------------
__launch_bounds__(512, 2)
__global__ void pass2_kernel(const bf16* __restrict__ hbuf, const bf16* __restrict__ w2b,
                             bf16* __restrict__ ybuf, const int* __restrict__ cnt,
                             const float* __restrict__ lw) {
  const int e = blockIdx.z;
  const int c = cnt[e];
  const int tm = blockIdx.y;
  if (tm * 256 >= c) return;
  const int tn = blockIdx.x;
  int be = 0;
#pragma unroll
  for (int k = 0; k < NE; ++k) if (k < e) be += cnt[k];

  __shared__ __align__(16) bf16 sA[2][256 * 64];
  __shared__ __align__(16) bf16 sB[2][256 * 64];
  char* const ldsA = (char*)&sA[0][0];
  char* const ldsB = (char*)&sB[0][0];

  const int tid = threadIdx.x;
  const int d0 = tid * 16, d1 = (tid + 512) * 16;
  const char* const bA = (const char*)hbuf;
  const char* const bB = (const char*)w2b;

  uint32_t oA[4], oB[4];
#pragma unroll
  for (int j = 0; j < 2; ++j) {
    const int ch = j ? (tid + 512) : tid;
    const int g = ch >> 8, q = (ch >> 5) & 7, r = ch & 31;
#pragma unroll
    for (int h = 0; h < 2; ++h) {
      const int rowt = h * 128 + g * 32 + r;
      int slot = tm * 256 + rowt; if (slot >= c) slot = c - 1;
      oA[h * 2 + j] = (uint32_t)((size_t)(be + slot) * (INTER * 2) + q * 16);
      oB[h * 2 + j] = (uint32_t)(((size_t)e * HID + tn * 256 + rowt) * (INTER * 2) + (size_t)q * 16);
    }
  }

  const int lane = tid & 63, wid = tid >> 6;
  const int wm = wid >> 2, wn = wid & 3;
  const int ln31 = lane & 31, kq2 = lane >> 5;
  int kcq[4];
#pragma unroll
  for (int ks = 0; ks < 4; ++ks) kcq[ks] = (ks * 2 + kq2) * 512;
  const int aOff = wm * 16384 + ln31 * 16;
  const int bOff = (wn >> 1) * 16384 + (wn & 1) * 8192 + ln31 * 16;

  f32x16 acc[4][2];
#pragma unroll
  for (int m = 0; m < 4; ++m)
#pragma unroll
    for (int n = 0; n < 2; ++n) acc[m][n] = (f32x16)(0.f);

  STAGE_A(0, 0); STAGE_A(1, 0); STAGE_B(0, 0); STAGE_B(1, 0);
  STAGE_A(0, 1); STAGE_A(1, 1); STAGE_B(0, 1);
  asm volatile("s_waitcnt vmcnt(6)" ::: "memory");
  BAR();

  bf16x8 aF[2][4], bF[2][4];
  int cur = 0;
  for (int t = 0; t < NT2; ++t, cur ^= 1) {
    const int curb = cur * 32768;
    // ---- ph1 ----
#pragma unroll
    for (int m = 0; m < 2; ++m)
#pragma unroll
      for (int ks = 0; ks < 4; ++ks) aF[m][ks] = RD_A(m, ks);
#pragma unroll
    for (int n = 0; n < 2; ++n)
#pragma unroll
      for (int ks = 0; ks < 4; ++ks) bF[n][ks] = RD_B(n, ks);
    LGKM0();
    BAR();
    if (t + 1 < NT2) { STAGE_B(1, t + 1); SCHED0(); }
    Q_MFMA32(aF, 0);
    BAR();
    // ---- ph2 ----
#pragma unroll
    for (int m = 0; m < 2; ++m)
#pragma unroll
      for (int ks = 0; ks < 4; ++ks) aF[m][ks] = RD_A(2 + m, ks);
    LGKM0();
    BAR();
    if (t + 2 < NT2) { STAGE_A(0, t + 2); STAGE_A(1, t + 2); STAGE_B(0, t + 2); SCHED0(); }
    Q_MFMA32(aF, 2);
    if (t + 2 < NT2) asm volatile("s_waitcnt vmcnt(6)" ::: "memory");
    else             asm volatile("s_waitcnt vmcnt(0)" ::: "memory");
    BAR();
  }

#pragma unroll
  for (int mf = 0; mf < 4; ++mf)
#pragma unroll
    for (int reg = 0; reg < 16; ++reg) {
      const int row = mf * 32 + (reg & 3) + 8 * (reg >> 2) + 4 * kq2;
      const int slot = tm * 256 + wm * 128 + row;
      if (slot < c) {
        const float wt = lw[e * TTOK + slot];
        bf16* yrow = ybuf + (size_t)(be + slot) * HID + tn * 256 + wn * 64;
#pragma unroll
        for (int nf = 0; nf < 2; ++nf)
          yrow[nf * 32 + ln31] = (bf16)(wt * acc[mf][nf][reg]);
      }
    }
}

extern "C" void kernel_launch(void* const* d_in, const int* in_sizes, int n_in,
                              void* d_out, int out_size, void* d_ws, size_t ws_size,
                              hipStream_t stream) {
  const float* x  = (const float*)d_in[0];
  const float* gw = (const float*)d_in[1];
  const float* w1 = (const float*)d_in[2];
  const float* w3 = (const float*)d_in[3];
  const float* w2 = (const float*)d_in[4];
  float* out = (float*)d_out;

  char* ws = (char*)d_ws;
  size_t off = 0;
  auto take = [&](size_t bytes) -> char* {
    char* p = ws + off;
    off += (bytes + 255) & ~(size_t)255;
    return p;
  };
  bf16* xb    = (bf16*)take((size_t)TTOK * HID * 2);
  bf16* w1b   = (bf16*)take((size_t)NE * INTER * HID * 2);   // w3b MUST follow contiguously
  bf16* w3b   = (bf16*)take((size_t)NE * INTER * HID * 2);
  bf16* w2b   = (bf16*)take((size_t)NE * HID * INTER * 2);
  bf16* hbuf  = (bf16*)take((size_t)TTOK * 2 * INTER * 2);
  bf16* ybuf  = (bf16*)take((size_t)TTOK * 2 * HID * 2);
  int*   topk_e = (int*)take(TTOK * 2 * 4);
  float* topk_w = (float*)take(TTOK * 2 * 4);
  int*   ltok   = (int*)take(NE * TTOK * 4);
  float* lwgt   = (float*)take(NE * TTOK * 4);
  int*   ppos   = (int*)take(TTOK * 2 * 4);
  int*   cntp   = (int*)take(64);
  if (off > ws_size) return;
  (void)w3b;

  cvtrt_kernel<<<8192 + TTOK / 4, 256, 0, stream>>>(w1, w3, w1b, x, gw, xb, topk_e, topk_w);
  gather_sorted<<<NE, 256, 0, stream>>>(topk_e, topk_w, cntp, ltok, lwgt, ppos);

  pass1_kernel<<<dim3(INTER / 128, TTOK / 256, NE + 1), 512, 0, stream>>>(
      xb, w1b, w2, w2b, hbuf, cntp, ltok);
  pass2_kernel<<<dim3(HID / 256, TTOK / 256, NE), 512, 0, stream>>>(
      hbuf, w2b, ybuf, cntp, lwgt);
  combine_kernel<<<TTOK, 256, 0, stream>>>(ybuf, topk_e, ppos, cntp, out);
}